// Round 3
// baseline (786.608 us; speedup 1.0000x reference)
//
#include <hip/hip_runtime.h>
#include <stdint.h>

typedef __bf16 bf16;
typedef __bf16 bf16x8 __attribute__((ext_vector_type(8)));
typedef __bf16 bf16x4 __attribute__((ext_vector_type(4)));
typedef __bf16 bf16x2 __attribute__((ext_vector_type(2)));
typedef float f32x4 __attribute__((ext_vector_type(4)));

static __device__ __forceinline__ float bflo(uint32_t u) { return __uint_as_float(u << 16); }
static __device__ __forceinline__ float bfhi(uint32_t u) { return __uint_as_float(u & 0xffff0000u); }

// ---------------- init ----------------

__global__ __launch_bounds__(256) void k_init(int* __restrict__ deg, float* __restrict__ stats,
                                              bf16* __restrict__ p, bf16* __restrict__ p2,
                                              int* __restrict__ ssrc, int N, int Ecap) {
    int i = blockIdx.x * 256 + threadIdx.x;
    if (i < N) deg[i] = 0;
    if (i < 3 * 512) stats[i] = 0.f;
    if (i < Ecap) ssrc[i] = N;  // pad -> zero row
    if (i < 128) p[(size_t)N * 128 + i] = (bf16)0.f;  // zero pad row (layers 0/1)
    if (i < 64) p2[(size_t)N * 64 + i] = (bf16)0.f;   // zero pad row (layer 2)
}

__global__ __launch_bounds__(256) void k_cvt_w(const float* __restrict__ wl, const float* __restrict__ wr,
                                               bf16* __restrict__ dst, int n) {
    int i = blockIdx.x * 256 + threadIdx.x;
    if (i >= n) return;
    dst[i] = (bf16)wl[i];
    dst[n + i] = (bf16)wr[i];
}

// ---------------- CSR build (XCD-sharded by dst range) ----------------

__global__ __launch_bounds__(256) void k_count(const int* __restrict__ dst, int* __restrict__ deg,
                                               int E, int B) {
    int g = blockIdx.x & 7;
    int lo = g * B, hi = lo + B;
    int br = blockIdx.x >> 3;
    int nb = gridDim.x >> 3;
    const int4* d4 = (const int4*)dst;
    int E4 = E >> 2;
    for (int i = br * 256 + threadIdx.x; i < E4; i += nb * 256) {
        int4 d = d4[i];
        if (d.x >= lo && d.x < hi) atomicAdd(&deg[d.x], 1);
        if (d.y >= lo && d.y < hi) atomicAdd(&deg[d.y], 1);
        if (d.z >= lo && d.z < hi) atomicAdd(&deg[d.z], 1);
        if (d.w >= lo && d.w < hi) atomicAdd(&deg[d.w], 1);
    }
}

__global__ __launch_bounds__(256) void k_scan1(const int* __restrict__ deg, int* __restrict__ rowptr,
                                               int* __restrict__ bsum, int N) {
    __shared__ int sh[256];
    int i = blockIdx.x * 256 + threadIdx.x;
    int v = (i < N) ? ((deg[i] + 7) & ~7) : 0;
    sh[threadIdx.x] = v;
    for (int off = 1; off < 256; off <<= 1) {
        __syncthreads();
        int t = (threadIdx.x >= off) ? sh[threadIdx.x - off] : 0;
        __syncthreads();
        sh[threadIdx.x] += t;
    }
    __syncthreads();
    if (i <= N) rowptr[i] = sh[threadIdx.x] - v;
    if (threadIdx.x == 255) bsum[blockIdx.x] = sh[255];
}

__global__ __launch_bounds__(512) void k_scan2(int* __restrict__ bsum, int nb) {
    __shared__ int sh[512];
    int v = (threadIdx.x < nb) ? bsum[threadIdx.x] : 0;
    sh[threadIdx.x] = v;
    for (int off = 1; off < 512; off <<= 1) {
        __syncthreads();
        int t = (threadIdx.x >= off) ? sh[threadIdx.x - off] : 0;
        __syncthreads();
        sh[threadIdx.x] += t;
    }
    __syncthreads();
    if (threadIdx.x < nb) bsum[threadIdx.x] = sh[threadIdx.x] - v;
}

__global__ __launch_bounds__(256) void k_scan3(int* __restrict__ rowptr, const int* __restrict__ bsum,
                                               int* __restrict__ cursor, int N) {
    int i = blockIdx.x * 256 + threadIdx.x;
    if (i <= N) {
        int v = rowptr[i] + bsum[i >> 8];
        rowptr[i] = v;
        if (i < N) cursor[i] = v;
    }
}

__global__ __launch_bounds__(256) void k_scatter(const int* __restrict__ src, const int* __restrict__ dst,
                                                 int* __restrict__ cursor, int* __restrict__ ssrc,
                                                 int E, int B) {
    int g = blockIdx.x & 7;
    int lo = g * B, hi = lo + B;
    int br = blockIdx.x >> 3;
    int nb = gridDim.x >> 3;
    const int4* d4 = (const int4*)dst;
    int E4 = E >> 2;
    for (int i = br * 256 + threadIdx.x; i < E4; i += nb * 256) {
        int4 d = d4[i];
        int e = i * 4;
        if (d.x >= lo && d.x < hi) { int pos = atomicAdd(&cursor[d.x], 1); ssrc[pos] = src[e]; }
        if (d.y >= lo && d.y < hi) { int pos = atomicAdd(&cursor[d.y], 1); ssrc[pos] = src[e + 1]; }
        if (d.z >= lo && d.z < hi) { int pos = atomicAdd(&cursor[d.z], 1); ssrc[pos] = src[e + 2]; }
        if (d.w >= lo && d.w < hi) { int pos = atomicAdd(&cursor[d.w], 1); ssrc[pos] = src[e + 3]; }
    }
}

// ---------------- fused GEMM ----------------
// MODE 0: A = x (f32 row-major). MODE 1: A = relu(o*cA+cB), o bf16 row-major [N][128].
// Out (row-major): P[N][Cout] bf16, R[N][Cout] bf16 (= X@Wr^T + bl).

template <int MODE>
__global__ __launch_bounds__(256) void k_gemm(const void* __restrict__ srcv, const float* __restrict__ cA,
                                              const float* __restrict__ cB, const bf16* __restrict__ W,
                                              const float* __restrict__ bl, bf16* __restrict__ P,
                                              bf16* __restrict__ R, int Cout, int N) {
    int wv = blockIdx.x * 4 + (threadIdx.x >> 6);
    int lane = threadIdx.x & 63;
    int node0 = wv * 16;
    if (node0 >= N) return;
    int m = lane & 15, quad = lane >> 4;
    bf16x8 a[4];
    if (MODE == 0) {
        const float* x = (const float*)srcv;
        const float* xr = x + (size_t)(node0 + m) * 128 + quad * 8;
#pragma unroll
        for (int t = 0; t < 4; t++) {
            float4 v0 = *(const float4*)(xr + t * 32);
            float4 v1 = *(const float4*)(xr + t * 32 + 4);
            bf16x8 f = {(bf16)v0.x, (bf16)v0.y, (bf16)v0.z, (bf16)v0.w,
                        (bf16)v1.x, (bf16)v1.y, (bf16)v1.z, (bf16)v1.w};
            a[t] = f;
        }
    } else {
        const bf16* o = (const bf16*)srcv;
#pragma unroll
        for (int t = 0; t < 4; t++) {
            int col0 = t * 32 + quad * 8;
            bf16x8 u = *(const bf16x8*)(o + (size_t)(node0 + m) * 128 + col0);
            float4 ca0 = *(const float4*)(cA + col0);
            float4 ca1 = *(const float4*)(cA + col0 + 4);
            float4 cb0 = *(const float4*)(cB + col0);
            float4 cb1 = *(const float4*)(cB + col0 + 4);
            float h0 = fmaxf(fmaf((float)u[0], ca0.x, cb0.x), 0.f);
            float h1 = fmaxf(fmaf((float)u[1], ca0.y, cb0.y), 0.f);
            float h2 = fmaxf(fmaf((float)u[2], ca0.z, cb0.z), 0.f);
            float h3 = fmaxf(fmaf((float)u[3], ca0.w, cb0.w), 0.f);
            float h4 = fmaxf(fmaf((float)u[4], ca1.x, cb1.x), 0.f);
            float h5 = fmaxf(fmaf((float)u[5], ca1.y, cb1.y), 0.f);
            float h6 = fmaxf(fmaf((float)u[6], ca1.z, cb1.z), 0.f);
            float h7 = fmaxf(fmaf((float)u[7], ca1.w, cb1.w), 0.f);
            bf16x8 f = {(bf16)h0, (bf16)h1, (bf16)h2, (bf16)h3,
                        (bf16)h4, (bf16)h5, (bf16)h6, (bf16)h7};
            a[t] = f;
        }
    }
    int ntiles = (2 * Cout) >> 4;
    int ntilesP = Cout >> 4;
    for (int ct = 0; ct < ntiles; ct++) {
        const bf16* wr = W + (size_t)(ct * 16 + m) * 128 + quad * 8;
        f32x4 acc = {0.f, 0.f, 0.f, 0.f};
        acc = __builtin_amdgcn_mfma_f32_16x16x32_bf16(a[0], *(const bf16x8*)(wr), acc, 0, 0, 0);
        acc = __builtin_amdgcn_mfma_f32_16x16x32_bf16(a[1], *(const bf16x8*)(wr + 32), acc, 0, 0, 0);
        acc = __builtin_amdgcn_mfma_f32_16x16x32_bf16(a[2], *(const bf16x8*)(wr + 64), acc, 0, 0, 0);
        acc = __builtin_amdgcn_mfma_f32_16x16x32_bf16(a[3], *(const bf16x8*)(wr + 96), acc, 0, 0, 0);
        if (ct < ntilesP) {
            bf16* pp = P + (size_t)(node0 + quad * 4) * Cout + ct * 16 + m;
            pp[0] = (bf16)acc[0];
            pp[Cout] = (bf16)acc[1];
            pp[2 * Cout] = (bf16)acc[2];
            pp[3 * Cout] = (bf16)acc[3];
        } else {
            int cc = (ct - ntilesP) * 16 + m;
            float bb = bl[cc];
            bf16* rr = R + (size_t)(node0 + quad * 4) * Cout + cc;
            rr[0] = (bf16)(acc[0] + bb);
            rr[Cout] = (bf16)(acc[1] + bb);
            rr[2 * Cout] = (bf16)(acc[2] + bb);
            rr[3 * Cout] = (bf16)(acc[3] + bb);
        }
    }
}

// ---------------- aggregate (full-row gather, single pass over edges) ----------------
// P row-major [N][C] bf16, C = LPN*8. LPN lanes x uint4 (16B) cover one 2*C-byte row.
// 64/LPN nodes per wave. Per 8-edge trip: 1 coalesced index lane-slice load +
// 8 ds_bpermute broadcasts + 8 gather insts (each inst: 64/LPN rows = <=8 cache lines).
// Block-level LDS reduction before global stats atomics.

template <int LPN>
__global__ __launch_bounds__(256, 6) void k_agg(const bf16* __restrict__ p, const bf16* __restrict__ r,
                                                const int* __restrict__ rowptr, const int* __restrict__ deg,
                                                const int* __restrict__ ssrc, bf16* __restrict__ o,
                                                float* __restrict__ ssum, float* __restrict__ ssq, int N) {
    constexpr int NODES = 64 / LPN;  // nodes per wave
    constexpr int C = LPN * 8;       // channels per row
    int wv = blockIdx.x * 4 + (threadIdx.x >> 6);
    int nwv = gridDim.x * 4;
    int lane = threadIdx.x & 63;
    int sub = lane & (LPN - 1);
    int grp = lane / LPN;
    const uint4* pu = (const uint4*)p;
    const uint4* ru = (const uint4*)r;
    __shared__ float ls[256];
    ls[threadIdx.x] = 0.f;
    __syncthreads();
    float s[8], q[8];
#pragma unroll
    for (int k = 0; k < 8; k++) { s[k] = 0.f; q[k] = 0.f; }
    int nchunk = (N + NODES - 1) / NODES;
    for (int c = wv; c < nchunk; c += nwv) {
        int n = c * NODES + grp;
        bool valid = n < N;
        int e = 0, iters = 0, d = 1;
        if (valid) {
            e = rowptr[n];
            iters = (rowptr[n + 1] - e) >> 3;
            d = deg[n];
        }
        float a[8];
#pragma unroll
        for (int k = 0; k < 8; k++) a[k] = 0.f;
        const int* sp = ssrc + e + (sub & 7);
        for (int t = 0; t < iters; t++) {
            int myidx = *sp;
            sp += 8;
#pragma unroll
            for (int j = 0; j < 8; j++) {
                int ij = __builtin_amdgcn_ds_bpermute((grp * LPN + j) * 4, myidx);
                uint4 u = pu[(size_t)ij * LPN + sub];
                a[0] += bflo(u.x);
                a[1] += bfhi(u.x);
                a[2] += bflo(u.y);
                a[3] += bfhi(u.y);
                a[4] += bflo(u.z);
                a[5] += bfhi(u.z);
                a[6] += bflo(u.w);
                a[7] += bfhi(u.w);
            }
        }
        if (valid) {
            float sc = 1.0f / (float)(d > 0 ? d : 1);
            uint4 rv = ru[(size_t)n * LPN + sub];
            float w0 = fmaf(a[0], sc, bflo(rv.x));
            float w1 = fmaf(a[1], sc, bfhi(rv.x));
            float w2 = fmaf(a[2], sc, bflo(rv.y));
            float w3 = fmaf(a[3], sc, bfhi(rv.y));
            float w4 = fmaf(a[4], sc, bflo(rv.z));
            float w5 = fmaf(a[5], sc, bfhi(rv.z));
            float w6 = fmaf(a[6], sc, bflo(rv.w));
            float w7 = fmaf(a[7], sc, bfhi(rv.w));
            bf16x8 ov = {(bf16)w0, (bf16)w1, (bf16)w2, (bf16)w3,
                         (bf16)w4, (bf16)w5, (bf16)w6, (bf16)w7};
            *(bf16x8*)(o + (size_t)n * C + sub * 8) = ov;
            s[0] += w0; q[0] += w0 * w0;
            s[1] += w1; q[1] += w1 * w1;
            s[2] += w2; q[2] += w2 * w2;
            s[3] += w3; q[3] += w3 * w3;
            s[4] += w4; q[4] += w4 * w4;
            s[5] += w5; q[5] += w5 * w5;
            s[6] += w6; q[6] += w6 * w6;
            s[7] += w7; q[7] += w7 * w7;
        }
    }
#pragma unroll
    for (int k = 0; k < 8; k++) {
#pragma unroll
        for (int msk = LPN; msk < 64; msk <<= 1) {
            s[k] += __shfl_xor(s[k], msk, 64);
            q[k] += __shfl_xor(q[k], msk, 64);
        }
    }
    if (grp == 0) {
#pragma unroll
        for (int k = 0; k < 8; k++) {
            atomicAdd(&ls[sub * 8 + k], s[k]);
            atomicAdd(&ls[128 + sub * 8 + k], q[k]);
        }
    }
    __syncthreads();
    int tid = threadIdx.x;
    if (tid < 128) {
        if (tid < C) atomicAdd(&ssum[tid], ls[tid]);
    } else {
        int c2 = tid - 128;
        if (c2 < C) atomicAdd(&ssq[c2], ls[tid]);
    }
}

// ---------------- BN finalize + final output ----------------

__global__ __launch_bounds__(128) void k_bn_fin(const float* __restrict__ ssum, const float* __restrict__ ssq,
                                                const float* __restrict__ gamma, const float* __restrict__ beta,
                                                float* __restrict__ cA, float* __restrict__ cB, int Cout, int N) {
    int c = threadIdx.x;
    if (c >= Cout) return;
    float m = ssum[c] / (float)N;
    float var = ssq[c] / (float)N - m * m;
    float a = gamma[c] * rsqrtf(var + 1e-5f);
    cA[c] = a;
    cB[c] = beta[c] - m * a;
}

__global__ __launch_bounds__(256) void k_norm_out(const bf16* __restrict__ o, const float* __restrict__ cA,
                                                  const float* __restrict__ cB, float* __restrict__ out, int N) {
    int i = blockIdx.x * 256 + threadIdx.x;
    if (i >= N * 8) return;
    int n = i >> 3;
    int col0 = (i & 7) * 8;
    bf16x8 u = *(const bf16x8*)(o + (size_t)n * 64 + col0);
    float4 ca0 = *(const float4*)(cA + col0);
    float4 ca1 = *(const float4*)(cA + col0 + 4);
    float4 cb0 = *(const float4*)(cB + col0);
    float4 cb1 = *(const float4*)(cB + col0 + 4);
    float4 w0, w1;
    w0.x = fmaf((float)u[0], ca0.x, cb0.x);
    w0.y = fmaf((float)u[1], ca0.y, cb0.y);
    w0.z = fmaf((float)u[2], ca0.z, cb0.z);
    w0.w = fmaf((float)u[3], ca0.w, cb0.w);
    w1.x = fmaf((float)u[4], ca1.x, cb1.x);
    w1.y = fmaf((float)u[5], ca1.y, cb1.y);
    w1.z = fmaf((float)u[6], ca1.z, cb1.z);
    w1.w = fmaf((float)u[7], ca1.w, cb1.w);
    *(float4*)(out + (size_t)n * 64 + col0) = w0;
    *(float4*)(out + (size_t)n * 64 + col0 + 4) = w1;
}

// ---------------- launch ----------------

static inline int cdiv(int a, int b) { return (a + b - 1) / b; }

extern "C" void kernel_launch(void* const* d_in, const int* in_sizes, int n_in,
                              void* d_out, int out_size, void* d_ws, size_t ws_size,
                              hipStream_t stream) {
    const float* x = (const float*)d_in[0];
    const int* ei = (const int*)d_in[1];
    const float* Wl[3] = {(const float*)d_in[2], (const float*)d_in[7], (const float*)d_in[12]};
    const float* bl[3] = {(const float*)d_in[3], (const float*)d_in[8], (const float*)d_in[13]};
    const float* Wr[3] = {(const float*)d_in[4], (const float*)d_in[9], (const float*)d_in[14]};
    const float* gam[3] = {(const float*)d_in[5], (const float*)d_in[10], (const float*)d_in[15]};
    const float* bet[3] = {(const float*)d_in[6], (const float*)d_in[11], (const float*)d_in[16]};

    const int N = in_sizes[0] / 128;  // 100000
    const int E = in_sizes[1] / 2;    // 1600000
    const int NP = N + 8;
    const int Ecap = E + 7 * ((N + 7) & ~7);
    const int B = (N + 7) / 8;  // dst-range bucket per XCD (CSR build)
    const int Couts[3] = {128, 128, 64};

    char* base = (char*)d_ws;
    size_t off = 0;
    auto alloc = [&](size_t bytes) -> void* {
        void* ptr = base + off;
        off += (bytes + 255) & ~(size_t)255;
        return ptr;
    };
    bf16* p = (bf16*)alloc((size_t)NP * 128 * 2);   // P rows, layers 0/1 (stride 128)
    bf16* p2 = (bf16*)alloc((size_t)NP * 64 * 2);   // P rows, layer 2 (stride 64)
    bf16* r = (bf16*)alloc((size_t)N * 128 * 2);
    bf16* o = (bf16*)alloc((size_t)N * 128 * 2);
    bf16* w0 = (bf16*)alloc(2 * 128 * 128 * 2);
    bf16* w1 = (bf16*)alloc(2 * 128 * 128 * 2);
    bf16* w2 = (bf16*)alloc(2 * 64 * 128 * 2);
    float* stats = (float*)alloc(3 * 512 * 4);
    int* rowptr = (int*)alloc((size_t)(N + 1) * 4);
    int* deg = (int*)alloc((size_t)N * 4);
    int* cursor = (int*)alloc((size_t)N * 4);
    int* bsum = (int*)alloc(512 * 4);
    int* ssrc = (int*)alloc((size_t)Ecap * 4);
    bf16* Wc[3] = {w0, w1, w2};

    const int* esrc = ei;
    const int* edst = ei + E;

    k_init<<<cdiv(Ecap, 256), 256, 0, stream>>>(deg, stats, p, p2, ssrc, N, Ecap);
    k_cvt_w<<<cdiv(128 * 128, 256), 256, 0, stream>>>(Wl[0], Wr[0], w0, 128 * 128);
    k_cvt_w<<<cdiv(128 * 128, 256), 256, 0, stream>>>(Wl[1], Wr[1], w1, 128 * 128);
    k_cvt_w<<<cdiv(64 * 128, 256), 256, 0, stream>>>(Wl[2], Wr[2], w2, 64 * 128);

    k_count<<<2048, 256, 0, stream>>>(edst, deg, E, B);
    int nb = cdiv(N + 1, 256);
    k_scan1<<<nb, 256, 0, stream>>>(deg, rowptr, bsum, N);
    k_scan2<<<1, 512, 0, stream>>>(bsum, nb);
    k_scan3<<<nb, 256, 0, stream>>>(rowptr, bsum, cursor, N);
    k_scatter<<<2048, 256, 0, stream>>>(esrc, edst, cursor, ssrc, E, B);

    const int AGG_BLOCKS = 2048;
    const int GEMM_BLOCKS = cdiv(N, 64);
    for (int l = 0; l < 3; l++) {
        int Cout = Couts[l];
        float* ss = stats + l * 512;
        float* sq = ss + 128;
        float* cA = ss + 256;
        float* cB = ss + 384;
        bf16* P = (l == 2) ? p2 : p;
        if (l == 0) {
            k_gemm<0><<<GEMM_BLOCKS, 256, 0, stream>>>(x, nullptr, nullptr, Wc[0], bl[0], P, r, Cout, N);
        } else {
            float* pA = stats + (l - 1) * 512 + 256;
            float* pB = stats + (l - 1) * 512 + 384;
            k_gemm<1><<<GEMM_BLOCKS, 256, 0, stream>>>(o, pA, pB, Wc[l], bl[l], P, r, Cout, N);
        }
        if (Cout == 128) {
            k_agg<16><<<AGG_BLOCKS, 256, 0, stream>>>(P, r, rowptr, deg, ssrc, o, ss, sq, N);
        } else {
            k_agg<8><<<AGG_BLOCKS, 256, 0, stream>>>(P, r, rowptr, deg, ssrc, o, ss, sq, N);
        }
        k_bn_fin<<<1, 128, 0, stream>>>(ss, sq, gam[l], bet[l], cA, cB, Cout, N);
        if (l == 2) {
            k_norm_out<<<cdiv(N * 8, 256), 256, 0, stream>>>(o, cA, cB, (float*)d_out, N);
        }
    }
}